// Round 1
// baseline (379.155 us; speedup 1.0000x reference)
//
#include <hip/hip_runtime.h>
#include <hip/hip_bf16.h>

// CrossAttention: b=4, n=1024, qs=256, heads=8, dim_head=64, bottleneck=40.
// Reference flattens heads into the sequence axis -> full 8192x8192 attention
// per batch over D=64.
//
// Pipeline:
//   k1: x -> (bottleneck, SiLU on K path) -> Q,K (b,8192,64) bf16, V^T (b,h,64,1024) bf16
//       softmax scale * log2(e) folded into Q.
//   k2: flash-style attention, 16x16x32 bf16 MFMA, no online max (scores bounded),
//       p = exp2(s'), row-sum reduced once at the end.
//   k3: out = O @ wo + bo (fp32)
//
// Workspace: Q 4MB + K 4MB + VT 4MB + O(fp32) 8MB = 20MB.

#define B_    4
#define H_    8
#define NSEQ  1024
#define SEQ   8192        // H_*NSEQ
#define DH    64
#define QS    256
#define INNER 512
#define QSCALE 0.18033688011112042f   // (1/sqrt(64)) * log2(e)

typedef __bf16 bf16x8 __attribute__((ext_vector_type(8)));
typedef float floatx4 __attribute__((ext_vector_type(4)));

// ---------------- kernel 1: QKV bottleneck projections ----------------
// grid 256 blocks (b * n/16), 256 threads. 16 rows of x per block.
__global__ __launch_bounds__(256) void qkv_kernel(
    const float* __restrict__ x,
    const float* __restrict__ wq1, const float* __restrict__ wq2,
    const float* __restrict__ wk1, const float* __restrict__ wk2,
    const float* __restrict__ wv1, const float* __restrict__ wv2,
    __hip_bfloat16* __restrict__ Qg, __hip_bfloat16* __restrict__ Kg,
    __hip_bfloat16* __restrict__ VTg)
{
  const int tid = threadIdx.x;
  const int blk = blockIdx.x;
  const int b  = blk >> 6;
  const int n0 = (blk & 63) << 4;

  __shared__ __align__(16) float xs[16][256];
  __shared__ __align__(16) float tb[3][16][40];   // bottleneck (silu applied for k)

  for (int i = tid; i < 16 * 256; i += 256) {
    const int r = i >> 8, c = i & 255;
    xs[r][c] = x[((size_t)b * NSEQ + n0 + r) * QS + c];
  }
  __syncthreads();

  // stage 1: tb = x @ w1  (3 proj x 16 rows x 10 bn-quads = 480 tasks)
  for (int qd = tid; qd < 480; qd += 256) {
    const int p   = qd / 160;
    const int rem = qd - p * 160;
    const int r   = rem / 10;
    const int bn  = (rem - r * 10) * 4;
    const float* w1 = (p == 0) ? wq1 : (p == 1) ? wk1 : wv1;
    float a0 = 0.f, a1 = 0.f, a2 = 0.f, a3 = 0.f;
    for (int c = 0; c < 256; ++c) {
      const float xv = xs[r][c];
      const float4 wv = *(const float4*)(w1 + c * 40 + bn);
      a0 += xv * wv.x; a1 += xv * wv.y; a2 += xv * wv.z; a3 += xv * wv.w;
    }
    if (p == 1) {   // SiLU on K bottleneck
      a0 = a0 / (1.f + __expf(-a0));
      a1 = a1 / (1.f + __expf(-a1));
      a2 = a2 / (1.f + __expf(-a2));
      a3 = a3 / (1.f + __expf(-a3));
    }
    tb[p][r][bn + 0] = a0; tb[p][r][bn + 1] = a1;
    tb[p][r][bn + 2] = a2; tb[p][r][bn + 3] = a3;
  }
  __syncthreads();

  // stage 2: q/k/v = tb @ w2. task = (p, rq, cq): thread owns 4 rows x 4 cols.
  for (int task = tid; task < 1536; task += 256) {
    const int cq = task & 127;
    const int pr = task >> 7;
    const int rq = pr & 3;
    const int p  = pr >> 2;
    const int c  = cq * 4, r0 = rq * 4;
    const float* w2 = (p == 0) ? wq2 : (p == 1) ? wk2 : wv2;
    float acc[4][4];
    #pragma unroll
    for (int i = 0; i < 4; ++i)
      #pragma unroll
      for (int j = 0; j < 4; ++j) acc[i][j] = 0.f;

    for (int jb = 0; jb < 10; ++jb) {
      const float4 w0 = *(const float4*)(w2 + (jb * 4 + 0) * INNER + c);
      const float4 w1r = *(const float4*)(w2 + (jb * 4 + 1) * INNER + c);
      const float4 w2r = *(const float4*)(w2 + (jb * 4 + 2) * INNER + c);
      const float4 w3 = *(const float4*)(w2 + (jb * 4 + 3) * INNER + c);
      #pragma unroll
      for (int ri = 0; ri < 4; ++ri) {
        const float4 tv = *(const float4*)(&tb[p][r0 + ri][jb * 4]);
        acc[ri][0] += tv.x * w0.x + tv.y * w1r.x + tv.z * w2r.x + tv.w * w3.x;
        acc[ri][1] += tv.x * w0.y + tv.y * w1r.y + tv.z * w2r.y + tv.w * w3.y;
        acc[ri][2] += tv.x * w0.z + tv.y * w1r.z + tv.z * w2r.z + tv.w * w3.z;
        acc[ri][3] += tv.x * w0.w + tv.y * w1r.w + tv.z * w2r.w + tv.w * w3.w;
      }
    }
    #pragma unroll
    for (int ri = 0; ri < 4; ++ri) {
      const int n = n0 + r0 + ri;
      #pragma unroll
      for (int ci = 0; ci < 4; ++ci) {
        const int cc = c + ci;
        const int h = cc >> 6, d = cc & 63;
        const float v = acc[ri][ci];
        if (p == 0)
          Qg[((size_t)b * SEQ + h * NSEQ + n) * DH + d] = __float2bfloat16(v * QSCALE);
        else if (p == 1)
          Kg[((size_t)b * SEQ + h * NSEQ + n) * DH + d] = __float2bfloat16(v);
        else
          VTg[(((size_t)b * H_ + h) * DH + d) * NSEQ + n] = __float2bfloat16(v);
      }
    }
  }
}

// ---------------- kernel 2: flash attention, bf16 MFMA ----------------
// grid (128 q-tiles, 4 batches), 256 threads = 4 waves, 16 q-rows per wave.
__global__ __launch_bounds__(256) void attn_kernel(
    const __hip_bfloat16* __restrict__ Qg,
    const __hip_bfloat16* __restrict__ Kg,
    const __hip_bfloat16* __restrict__ VTg,
    float* __restrict__ Og)
{
  // rows padded 64 -> 72 elements (144B) to break the 128B bank stride
  __shared__ __align__(16) __hip_bfloat16 Ks[64 * 72];      // K[kv][d]
  __shared__ __align__(16) __hip_bfloat16 Vs[64 * 72];      // V^T[d][kv]
  __shared__ __align__(16) __hip_bfloat16 Ps[4][16 * 72];   // per-wave P tile

  const int tid  = threadIdx.x;
  const int wave = tid >> 6;
  const int lane = tid & 63;
  const int lrow = lane & 15;
  const int quad = lane >> 4;
  const int b     = blockIdx.y;
  const int qbase = blockIdx.x * 64;

  // Q fragments (A layout: m=lane&15, k=quad*8+j), held for the whole loop
  const size_t qrow = (size_t)b * SEQ + qbase + wave * 16 + lrow;
  const bf16x8 qf0 = *reinterpret_cast<const bf16x8*>(Qg + qrow * DH + quad * 8);
  const bf16x8 qf1 = *reinterpret_cast<const bf16x8*>(Qg + qrow * DH + 32 + quad * 8);

  floatx4 oacc[4];
  #pragma unroll
  for (int i = 0; i < 4; ++i) oacc[i] = (floatx4){0.f, 0.f, 0.f, 0.f};
  float psum[4] = {0.f, 0.f, 0.f, 0.f};

  __hip_bfloat16* Pw = &Ps[wave][0];

  for (int t = 0; t < SEQ / 64; ++t) {
    __syncthreads();          // previous iter's LDS reads done before restage
    const int j0 = t * 64;
    const int h  = j0 >> 10;
    const int nn = j0 & 1023;
    for (int i = tid; i < 512; i += 256) {     // 64x64 bf16 tiles, float4 chunks
      const int r = i >> 3, c8 = (i & 7) * 8;
      *reinterpret_cast<float4*>(&Ks[r * 72 + c8]) =
          *reinterpret_cast<const float4*>(Kg + ((size_t)b * SEQ + j0 + r) * DH + c8);
      *reinterpret_cast<float4*>(&Vs[r * 72 + c8]) =
          *reinterpret_cast<const float4*>(VTg + (((size_t)b * H_ + h) * DH + r) * NSEQ + nn + c8);
    }
    __syncthreads();

    // S = Q K^T  (scores already scaled by 1/sqrt(d)*log2e via Q)
    floatx4 sc[4];
    #pragma unroll
    for (int nt = 0; nt < 4; ++nt) {
      floatx4 acc = (floatx4){0.f, 0.f, 0.f, 0.f};
      const bf16x8 b0 = *reinterpret_cast<const bf16x8*>(&Ks[(nt * 16 + lrow) * 72 + quad * 8]);
      const bf16x8 b1 = *reinterpret_cast<const bf16x8*>(&Ks[(nt * 16 + lrow) * 72 + 32 + quad * 8]);
      acc = __builtin_amdgcn_mfma_f32_16x16x32_bf16(qf0, b0, acc, 0, 0, 0);
      acc = __builtin_amdgcn_mfma_f32_16x16x32_bf16(qf1, b1, acc, 0, 0, 0);
      sc[nt] = acc;
    }

    // p = exp2(s); no online max needed (|s| bounded ~10, fp32 range is ample)
    #pragma unroll
    for (int nt = 0; nt < 4; ++nt) {
      #pragma unroll
      for (int r = 0; r < 4; ++r) {
        const float p = exp2f(sc[nt][r]);
        sc[nt][r] = p;
        psum[r] += p;       // this lane's column, row quad*4+r
      }
    }

    // P: C-layout regs -> LDS (row-major 16x64, padded 72)
    #pragma unroll
    for (int nt = 0; nt < 4; ++nt)
      #pragma unroll
      for (int r = 0; r < 4; ++r)
        Pw[(quad * 4 + r) * 72 + nt * 16 + lrow] = __float2bfloat16(sc[nt][r]);

    // O += P V   (A = P from LDS, B = V^T rows from LDS)
    #pragma unroll
    for (int s = 0; s < 2; ++s) {
      const bf16x8 af = *reinterpret_cast<const bf16x8*>(&Pw[lrow * 72 + s * 32 + quad * 8]);
      #pragma unroll
      for (int dnt = 0; dnt < 4; ++dnt) {
        const bf16x8 bf = *reinterpret_cast<const bf16x8*>(&Vs[(dnt * 16 + lrow) * 72 + s * 32 + quad * 8]);
        oacc[dnt] = __builtin_amdgcn_mfma_f32_16x16x32_bf16(af, bf, oacc[dnt], 0, 0, 0);
      }
    }
  }

  // row sums: reduce across the 16 lanes of each quad (once, at the end)
  #pragma unroll
  for (int r = 0; r < 4; ++r) {
    float s = psum[r];
    #pragma unroll
    for (int off = 1; off < 16; off <<= 1)
      s += __shfl_xor(s, off, 64);
    psum[r] = s;
  }

  #pragma unroll
  for (int r = 0; r < 4; ++r) {
    const float inv = 1.0f / psum[r];
    const size_t row = (size_t)b * SEQ + qbase + wave * 16 + quad * 4 + r;
    #pragma unroll
    for (int dnt = 0; dnt < 4; ++dnt)
      Og[row * DH + dnt * 16 + lrow] = oacc[dnt][r] * inv;
  }
}

// ---------------- kernel 3: out = O @ wo + bo ----------------
// grid 256 blocks (b * n/16), 256 threads; thread owns 4 rows x 4 cols.
__global__ __launch_bounds__(256) void out_kernel(
    const float* __restrict__ Og, const float* __restrict__ wo,
    const float* __restrict__ bo, float* __restrict__ out)
{
  const int tid = threadIdx.x;
  const int b  = blockIdx.x >> 6;
  const int n0 = (blockIdx.x & 63) << 4;

  __shared__ __align__(16) float os[16][512];   // gathered (n, h*64+d) rows
  for (int i = tid; i < 16 * 512; i += 256) {
    const int r = i >> 9, cc = i & 511;
    os[r][cc] = Og[((size_t)b * SEQ + (cc >> 6) * NSEQ + n0 + r) * DH + (cc & 63)];
  }
  __syncthreads();

  const int oq = tid & 63, rq = tid >> 6;
  const int o = oq * 4, r0 = rq * 4;
  float acc[4][4];
  #pragma unroll
  for (int i = 0; i < 4; ++i)
    #pragma unroll
    for (int j = 0; j < 4; ++j) acc[i][j] = 0.f;

  for (int jb = 0; jb < 128; ++jb) {
    const float4 w0 = *(const float4*)(wo + (jb * 4 + 0) * QS + o);
    const float4 w1 = *(const float4*)(wo + (jb * 4 + 1) * QS + o);
    const float4 w2 = *(const float4*)(wo + (jb * 4 + 2) * QS + o);
    const float4 w3 = *(const float4*)(wo + (jb * 4 + 3) * QS + o);
    #pragma unroll
    for (int ri = 0; ri < 4; ++ri) {
      const float4 ov = *(const float4*)(&os[r0 + ri][jb * 4]);
      acc[ri][0] += ov.x * w0.x + ov.y * w1.x + ov.z * w2.x + ov.w * w3.x;
      acc[ri][1] += ov.x * w0.y + ov.y * w1.y + ov.z * w2.y + ov.w * w3.y;
      acc[ri][2] += ov.x * w0.z + ov.y * w1.z + ov.z * w2.z + ov.w * w3.z;
      acc[ri][3] += ov.x * w0.w + ov.y * w1.w + ov.z * w2.w + ov.w * w3.w;
    }
  }

  const float4 bv = *(const float4*)(bo + o);
  #pragma unroll
  for (int ri = 0; ri < 4; ++ri) {
    float4 res;
    res.x = acc[ri][0] + bv.x;
    res.y = acc[ri][1] + bv.y;
    res.z = acc[ri][2] + bv.z;
    res.w = acc[ri][3] + bv.w;
    *(float4*)(out + ((size_t)b * NSEQ + n0 + r0 + ri) * QS + o) = res;
  }
}

extern "C" void kernel_launch(void* const* d_in, const int* in_sizes, int n_in,
                              void* d_out, int out_size, void* d_ws, size_t ws_size,
                              hipStream_t stream) {
  const float* x   = (const float*)d_in[0];
  const float* wq1 = (const float*)d_in[1];
  const float* wq2 = (const float*)d_in[2];
  const float* wk1 = (const float*)d_in[3];
  const float* wk2 = (const float*)d_in[4];
  const float* wv1 = (const float*)d_in[5];
  const float* wv2 = (const float*)d_in[6];
  const float* wo  = (const float*)d_in[7];
  const float* bo  = (const float*)d_in[8];
  float* out = (float*)d_out;

  // workspace layout: Q | K | VT (bf16) | O (fp32)  = 20 MB total
  __hip_bfloat16* Qg  = (__hip_bfloat16*)d_ws;
  __hip_bfloat16* Kg  = Qg + (size_t)B_ * SEQ * DH;
  __hip_bfloat16* VTg = Kg + (size_t)B_ * SEQ * DH;
  float*          Og  = (float*)(VTg + (size_t)B_ * SEQ * DH);

  qkv_kernel<<<256, 256, 0, stream>>>(x, wq1, wq2, wk1, wk2, wv1, wv2, Qg, Kg, VTg);
  attn_kernel<<<dim3(SEQ / 64, B_), 256, 0, stream>>>(Qg, Kg, VTg, Og);
  out_kernel<<<256, 256, 0, stream>>>(Og, wo, bo, out);
}

// Round 2
// 343.923 us; speedup vs baseline: 1.1024x; 1.1024x over previous
//
#include <hip/hip_runtime.h>
#include <hip/hip_bf16.h>

// CrossAttention: b=4, n=1024, qs=256, heads=8, dim_head=64, bottleneck=40.
// Attention is a full 8192x8192 softmax-attention per batch over D=64.
//
// R2: attention restructured. K/V MFMA B-fragments are loaded DIRECTLY from
// global (their fragment layout == contiguous 16B of the K / V^T arrays), so
// LDS carries only the P (softmax probs) round-trip. Q fragments live in
// registers for the whole KV loop. K/V frags prefetched one tile ahead.
//
// Workspace: Q 4MB + K 4MB + VT 4MB (bf16) + O 8MB (fp32) = 20MB.

#define B_    4
#define H_    8
#define NSEQ  1024
#define SEQ   8192        // H_*NSEQ
#define DH    64
#define QS    256
#define INNER 512
#define QSCALE 0.18033688011112042f   // (1/sqrt(64)) * log2(e)

typedef __bf16 bf16x8 __attribute__((ext_vector_type(8)));
typedef float floatx4 __attribute__((ext_vector_type(4)));

// ---------------- kernel 1: QKV bottleneck projections ----------------
__global__ __launch_bounds__(256) void qkv_kernel(
    const float* __restrict__ x,
    const float* __restrict__ wq1, const float* __restrict__ wq2,
    const float* __restrict__ wk1, const float* __restrict__ wk2,
    const float* __restrict__ wv1, const float* __restrict__ wv2,
    __hip_bfloat16* __restrict__ Qg, __hip_bfloat16* __restrict__ Kg,
    __hip_bfloat16* __restrict__ VTg)
{
  const int tid = threadIdx.x;
  const int blk = blockIdx.x;
  const int b  = blk >> 6;
  const int n0 = (blk & 63) << 4;

  __shared__ __align__(16) float xs[16][256];
  __shared__ __align__(16) float tb[3][16][40];

  for (int i = tid; i < 16 * 256; i += 256) {
    const int r = i >> 8, c = i & 255;
    xs[r][c] = x[((size_t)b * NSEQ + n0 + r) * QS + c];
  }
  __syncthreads();

  for (int qd = tid; qd < 480; qd += 256) {
    const int p   = qd / 160;
    const int rem = qd - p * 160;
    const int r   = rem / 10;
    const int bn  = (rem - r * 10) * 4;
    const float* w1 = (p == 0) ? wq1 : (p == 1) ? wk1 : wv1;
    float a0 = 0.f, a1 = 0.f, a2 = 0.f, a3 = 0.f;
    for (int c = 0; c < 256; ++c) {
      const float xv = xs[r][c];
      const float4 wv = *(const float4*)(w1 + c * 40 + bn);
      a0 += xv * wv.x; a1 += xv * wv.y; a2 += xv * wv.z; a3 += xv * wv.w;
    }
    if (p == 1) {
      a0 = a0 / (1.f + __expf(-a0));
      a1 = a1 / (1.f + __expf(-a1));
      a2 = a2 / (1.f + __expf(-a2));
      a3 = a3 / (1.f + __expf(-a3));
    }
    tb[p][r][bn + 0] = a0; tb[p][r][bn + 1] = a1;
    tb[p][r][bn + 2] = a2; tb[p][r][bn + 3] = a3;
  }
  __syncthreads();

  for (int task = tid; task < 1536; task += 256) {
    const int cq = task & 127;
    const int pr = task >> 7;
    const int rq = pr & 3;
    const int p  = pr >> 2;
    const int c  = cq * 4, r0 = rq * 4;
    const float* w2 = (p == 0) ? wq2 : (p == 1) ? wk2 : wv2;
    float acc[4][4];
    #pragma unroll
    for (int i = 0; i < 4; ++i)
      #pragma unroll
      for (int j = 0; j < 4; ++j) acc[i][j] = 0.f;

    for (int jb = 0; jb < 10; ++jb) {
      const float4 w0 = *(const float4*)(w2 + (jb * 4 + 0) * INNER + c);
      const float4 w1r = *(const float4*)(w2 + (jb * 4 + 1) * INNER + c);
      const float4 w2r = *(const float4*)(w2 + (jb * 4 + 2) * INNER + c);
      const float4 w3 = *(const float4*)(w2 + (jb * 4 + 3) * INNER + c);
      #pragma unroll
      for (int ri = 0; ri < 4; ++ri) {
        const float4 tv = *(const float4*)(&tb[p][r0 + ri][jb * 4]);
        acc[ri][0] += tv.x * w0.x + tv.y * w1r.x + tv.z * w2r.x + tv.w * w3.x;
        acc[ri][1] += tv.x * w0.y + tv.y * w1r.y + tv.z * w2r.y + tv.w * w3.y;
        acc[ri][2] += tv.x * w0.z + tv.y * w1r.z + tv.z * w2r.z + tv.w * w3.z;
        acc[ri][3] += tv.x * w0.w + tv.y * w1r.w + tv.z * w2r.w + tv.w * w3.w;
      }
    }
    #pragma unroll
    for (int ri = 0; ri < 4; ++ri) {
      const int n = n0 + r0 + ri;
      #pragma unroll
      for (int ci = 0; ci < 4; ++ci) {
        const int cc = c + ci;
        const int h = cc >> 6, d = cc & 63;
        const float v = acc[ri][ci];
        if (p == 0)
          Qg[((size_t)b * SEQ + h * NSEQ + n) * DH + d] = __float2bfloat16(v * QSCALE);
        else if (p == 1)
          Kg[((size_t)b * SEQ + h * NSEQ + n) * DH + d] = __float2bfloat16(v);
        else
          VTg[(((size_t)b * H_ + h) * DH + d) * NSEQ + n] = __float2bfloat16(v);
      }
    }
  }
}

// ---------------- kernel 2: flash attention, K/V frags from global ----------------
// grid (128 q-tiles of 64 rows, 4 batches), 256 threads = 4 waves.
// Wave roles: QK^T n-split (wave w -> kv cols w*16..w*16+15);
//             PV 2x2 (wi = m-pair, wj = d-pair).
__global__ __launch_bounds__(256, 2) void attn_kernel(
    const __hip_bfloat16* __restrict__ Qg,
    const __hip_bfloat16* __restrict__ Kg,
    const __hip_bfloat16* __restrict__ VTg,
    float* __restrict__ Og)
{
  __shared__ __align__(16) __hip_bfloat16 Ps[64 * 72];   // P rows q, cols kv (pad 72)
  __shared__ float psums[4][64];

  const int tid  = threadIdx.x;
  const int wave = tid >> 6;
  const int lane = tid & 63;
  const int lrow = lane & 15;
  const int quad = lane >> 4;
  const int wi   = wave >> 1;          // PV m-pair
  const int wj   = wave & 1;           // PV d-pair
  const int b    = blockIdx.y;
  const int qbase = blockIdx.x * 64;

  const __hip_bfloat16* Qb = Qg + ((size_t)b * SEQ + qbase) * DH;
  const __hip_bfloat16* Kb = Kg + (size_t)b * SEQ * DH;
  const __hip_bfloat16* Vb = VTg + (size_t)b * (H_ * DH * NSEQ);

  // Q fragments in registers for the whole loop (A-layout == contiguous 16B)
  bf16x8 qf[4][2];
  #pragma unroll
  for (int mt = 0; mt < 4; ++mt)
    #pragma unroll
    for (int s = 0; s < 2; ++s)
      qf[mt][s] = *reinterpret_cast<const bf16x8*>(Qb + (mt * 16 + lrow) * DH + s * 32 + quad * 8);

  floatx4 oacc[2][2];
  #pragma unroll
  for (int mi = 0; mi < 2; ++mi)
    #pragma unroll
    for (int dj = 0; dj < 2; ++dj)
      oacc[mi][dj] = (floatx4){0.f, 0.f, 0.f, 0.f};
  float psum[4][4];
  #pragma unroll
  for (int mt = 0; mt < 4; ++mt)
    #pragma unroll
    for (int r = 0; r < 4; ++r) psum[mt][r] = 0.f;

  const int krow = wave * 16 + lrow;   // this wave's K rows (QK b-frags)

  // current-tile K/V fragments (B-layout == contiguous 16B of K / V^T)
  bf16x8 kc[2], vc[2][2];
  #pragma unroll
  for (int s = 0; s < 2; ++s)
    kc[s] = *(const bf16x8*)(Kb + (size_t)krow * DH + s * 32 + quad * 8);
  #pragma unroll
  for (int dj = 0; dj < 2; ++dj)
    #pragma unroll
    for (int s = 0; s < 2; ++s)
      vc[dj][s] = *(const bf16x8*)(Vb + (size_t)((wj * 2 + dj) * 16 + lrow) * NSEQ + s * 32 + quad * 8);

  __hip_bfloat16* Pwr = Ps + (quad * 4) * 72 + wave * 16 + lrow;          // + (mt*16+r)*72
  const __hip_bfloat16* Par = Ps + ((wi * 2) * 16 + lrow) * 72 + quad * 8; // + mi*1152 + s*32

  for (int t = 0; t < SEQ / 64; ++t) {
    // ---- prefetch next KV tile's fragments (consumed next iteration) ----
    bf16x8 kn[2], vn[2][2];
    {
      const int tn  = (t < SEQ / 64 - 1) ? t + 1 : t;   // clamp: last prefetch unused
      const int j0n = tn * 64;
      const int hn  = j0n >> 10;
      const int nnn = j0n & 1023;
      #pragma unroll
      for (int s = 0; s < 2; ++s)
        kn[s] = *(const bf16x8*)(Kb + (size_t)(j0n + krow) * DH + s * 32 + quad * 8);
      #pragma unroll
      for (int dj = 0; dj < 2; ++dj)
        #pragma unroll
        for (int s = 0; s < 2; ++s)
          vn[dj][s] = *(const bf16x8*)(Vb + (size_t)(hn * DH + (wj * 2 + dj) * 16 + lrow) * NSEQ
                                       + nnn + s * 32 + quad * 8);
    }

    // ---- S = Q K^T for this wave's 16 kv cols ----
    floatx4 sc[4];
    #pragma unroll
    for (int mt = 0; mt < 4; ++mt) {
      floatx4 a = (floatx4){0.f, 0.f, 0.f, 0.f};
      a = __builtin_amdgcn_mfma_f32_16x16x32_bf16(qf[mt][0], kc[0], a, 0, 0, 0);
      a = __builtin_amdgcn_mfma_f32_16x16x32_bf16(qf[mt][1], kc[1], a, 0, 0, 0);
      sc[mt] = a;
    }

    // ---- p = exp2(s), running row-sums (scores bounded: no online max) ----
    #pragma unroll
    for (int mt = 0; mt < 4; ++mt)
      #pragma unroll
      for (int r = 0; r < 4; ++r) {
        const float p = __builtin_amdgcn_exp2f(sc[mt][r]);
        sc[mt][r] = p;
        psum[mt][r] += p;
      }

    __syncthreads();   // all waves done reading Ps of tile t-1
    #pragma unroll
    for (int mt = 0; mt < 4; ++mt)
      #pragma unroll
      for (int r = 0; r < 4; ++r)
        Pwr[(mt * 16 + r) * 72] = __float2bfloat16(sc[mt][r]);
    __syncthreads();   // Ps of tile t visible

    // ---- O += P V  (A = P from LDS, B = V^T frags already in registers) ----
    #pragma unroll
    for (int mi = 0; mi < 2; ++mi) {
      #pragma unroll
      for (int s = 0; s < 2; ++s) {
        const bf16x8 pa = *reinterpret_cast<const bf16x8*>(Par + mi * 1152 + s * 32);
        #pragma unroll
        for (int dj = 0; dj < 2; ++dj)
          oacc[mi][dj] = __builtin_amdgcn_mfma_f32_16x16x32_bf16(pa, vc[dj][s], oacc[mi][dj], 0, 0, 0);
      }
    }

    // rotate prefetched fragments in
    #pragma unroll
    for (int s = 0; s < 2; ++s) kc[s] = kn[s];
    #pragma unroll
    for (int dj = 0; dj < 2; ++dj)
      #pragma unroll
      for (int s = 0; s < 2; ++s) vc[dj][s] = vn[dj][s];
  }

  // ---- row-sum completion: 16-lane shuffle reduce, then cross-wave via LDS ----
  #pragma unroll
  for (int mt = 0; mt < 4; ++mt)
    #pragma unroll
    for (int r = 0; r < 4; ++r) {
      float s = psum[mt][r];
      #pragma unroll
      for (int off = 1; off < 16; off <<= 1)
        s += __shfl_xor(s, off, 64);
      psum[mt][r] = s;
    }
  if (lrow == 0) {
    #pragma unroll
    for (int mt = 0; mt < 4; ++mt)
      #pragma unroll
      for (int r = 0; r < 4; ++r)
        psums[wave][mt * 16 + quad * 4 + r] = psum[mt][r];
  }
  __syncthreads();

  // ---- normalize and write O ----
  #pragma unroll
  for (int mi = 0; mi < 2; ++mi)
    #pragma unroll
    for (int r = 0; r < 4; ++r) {
      const int q = (wi * 2 + mi) * 16 + quad * 4 + r;
      const float tot = psums[0][q] + psums[1][q] + psums[2][q] + psums[3][q];
      const float inv = 1.0f / tot;
      const size_t row = (size_t)b * SEQ + qbase + q;
      #pragma unroll
      for (int dj = 0; dj < 2; ++dj)
        Og[row * DH + (wj * 2 + dj) * 16 + lrow] = oacc[mi][dj][r] * inv;
    }
}

// ---------------- kernel 3: out = O @ wo + bo ----------------
__global__ __launch_bounds__(256) void out_kernel(
    const float* __restrict__ Og, const float* __restrict__ wo,
    const float* __restrict__ bo, float* __restrict__ out)
{
  const int tid = threadIdx.x;
  const int b  = blockIdx.x >> 6;
  const int n0 = (blockIdx.x & 63) << 4;

  __shared__ __align__(16) float os[16][512];
  for (int i = tid; i < 16 * 512; i += 256) {
    const int r = i >> 9, cc = i & 511;
    os[r][cc] = Og[((size_t)b * SEQ + (cc >> 6) * NSEQ + n0 + r) * DH + (cc & 63)];
  }
  __syncthreads();

  const int oq = tid & 63, rq = tid >> 6;
  const int o = oq * 4, r0 = rq * 4;
  float acc[4][4];
  #pragma unroll
  for (int i = 0; i < 4; ++i)
    #pragma unroll
    for (int j = 0; j < 4; ++j) acc[i][j] = 0.f;

  for (int jb = 0; jb < 128; ++jb) {
    const float4 w0 = *(const float4*)(wo + (jb * 4 + 0) * QS + o);
    const float4 w1 = *(const float4*)(wo + (jb * 4 + 1) * QS + o);
    const float4 w2 = *(const float4*)(wo + (jb * 4 + 2) * QS + o);
    const float4 w3 = *(const float4*)(wo + (jb * 4 + 3) * QS + o);
    #pragma unroll
    for (int ri = 0; ri < 4; ++ri) {
      const float4 ov = *(const float4*)(&os[r0 + ri][jb * 4]);
      acc[ri][0] += ov.x * w0.x + ov.y * w1.x + ov.z * w2.x + ov.w * w3.x;
      acc[ri][1] += ov.x * w0.y + ov.y * w1.y + ov.z * w2.y + ov.w * w3.y;
      acc[ri][2] += ov.x * w0.z + ov.y * w1.z + ov.z * w2.z + ov.w * w3.z;
      acc[ri][3] += ov.x * w0.w + ov.y * w1.w + ov.z * w2.w + ov.w * w3.w;
    }
  }

  const float4 bv = *(const float4*)(bo + o);
  #pragma unroll
  for (int ri = 0; ri < 4; ++ri) {
    float4 res;
    res.x = acc[ri][0] + bv.x;
    res.y = acc[ri][1] + bv.y;
    res.z = acc[ri][2] + bv.z;
    res.w = acc[ri][3] + bv.w;
    *(float4*)(out + ((size_t)b * NSEQ + n0 + r0 + ri) * QS + o) = res;
  }
}

extern "C" void kernel_launch(void* const* d_in, const int* in_sizes, int n_in,
                              void* d_out, int out_size, void* d_ws, size_t ws_size,
                              hipStream_t stream) {
  const float* x   = (const float*)d_in[0];
  const float* wq1 = (const float*)d_in[1];
  const float* wq2 = (const float*)d_in[2];
  const float* wk1 = (const float*)d_in[3];
  const float* wk2 = (const float*)d_in[4];
  const float* wv1 = (const float*)d_in[5];
  const float* wv2 = (const float*)d_in[6];
  const float* wo  = (const float*)d_in[7];
  const float* bo  = (const float*)d_in[8];
  float* out = (float*)d_out;

  __hip_bfloat16* Qg  = (__hip_bfloat16*)d_ws;
  __hip_bfloat16* Kg  = Qg + (size_t)B_ * SEQ * DH;
  __hip_bfloat16* VTg = Kg + (size_t)B_ * SEQ * DH;
  float*          Og  = (float*)(VTg + (size_t)B_ * SEQ * DH);

  qkv_kernel<<<256, 256, 0, stream>>>(x, wq1, wq2, wk1, wk2, wv1, wv2, Qg, Kg, VTg);
  attn_kernel<<<dim3(SEQ / 64, B_), 256, 0, stream>>>(Qg, Kg, VTg, Og);
  out_kernel<<<256, 256, 0, stream>>>(Og, wo, bo, out);
}

// Round 3
// 340.932 us; speedup vs baseline: 1.1121x; 1.0088x over previous
//
#include <hip/hip_runtime.h>
#include <hip/hip_bf16.h>

// CrossAttention: b=4, n=1024, qs=256, heads=8, dim_head=64, bottleneck=40.
// Attention = full 8192x8192 softmax-attention per batch over D=64.
//
// R3: zero-barrier attention main loop. S^T = K*Q^T puts P in the exact
// in-lane layout PV needs (with a consistent k-relabeling across a strip
// pair), so P never touches LDS. kv split 4-ways across waves; one final
// LDS reduction merges partial O and softmax denominators.
//
// Workspace: Q 4MB + K 4MB + VT 4MB (bf16) + O 8MB (fp32) = 20MB.

#define B_    4
#define H_    8
#define NSEQ  1024
#define SEQ   8192        // H_*NSEQ
#define DH    64
#define QS    256
#define INNER 512
#define QSCALE 0.18033688011112042f   // (1/sqrt(64)) * log2(e)

typedef __bf16 bf16x8 __attribute__((ext_vector_type(8)));
typedef __bf16 bf16x4 __attribute__((ext_vector_type(4)));
typedef float floatx4 __attribute__((ext_vector_type(4)));

// ---------------- kernel 1: QKV bottleneck projections ----------------
__global__ __launch_bounds__(256) void qkv_kernel(
    const float* __restrict__ x,
    const float* __restrict__ wq1, const float* __restrict__ wq2,
    const float* __restrict__ wk1, const float* __restrict__ wk2,
    const float* __restrict__ wv1, const float* __restrict__ wv2,
    __hip_bfloat16* __restrict__ Qg, __hip_bfloat16* __restrict__ Kg,
    __hip_bfloat16* __restrict__ VTg)
{
  const int tid = threadIdx.x;
  const int blk = blockIdx.x;
  const int b  = blk >> 6;
  const int n0 = (blk & 63) << 4;

  __shared__ __align__(16) float xs[16][256];
  __shared__ __align__(16) float tb[3][16][40];

  for (int i = tid; i < 16 * 256; i += 256) {
    const int r = i >> 8, c = i & 255;
    xs[r][c] = x[((size_t)b * NSEQ + n0 + r) * QS + c];
  }
  __syncthreads();

  for (int qd = tid; qd < 480; qd += 256) {
    const int p   = qd / 160;
    const int rem = qd - p * 160;
    const int r   = rem / 10;
    const int bn  = (rem - r * 10) * 4;
    const float* w1 = (p == 0) ? wq1 : (p == 1) ? wk1 : wv1;
    float a0 = 0.f, a1 = 0.f, a2 = 0.f, a3 = 0.f;
    for (int c4 = 0; c4 < 64; ++c4) {
      const float4 xv = *(const float4*)(&xs[r][c4 * 4]);
      const float4 wa = *(const float4*)(w1 + (c4 * 4 + 0) * 40 + bn);
      const float4 wb = *(const float4*)(w1 + (c4 * 4 + 1) * 40 + bn);
      const float4 wc = *(const float4*)(w1 + (c4 * 4 + 2) * 40 + bn);
      const float4 wd = *(const float4*)(w1 + (c4 * 4 + 3) * 40 + bn);
      a0 += xv.x * wa.x + xv.y * wb.x + xv.z * wc.x + xv.w * wd.x;
      a1 += xv.x * wa.y + xv.y * wb.y + xv.z * wc.y + xv.w * wd.y;
      a2 += xv.x * wa.z + xv.y * wb.z + xv.z * wc.z + xv.w * wd.z;
      a3 += xv.x * wa.w + xv.y * wb.w + xv.z * wc.w + xv.w * wd.w;
    }
    if (p == 1) {   // SiLU on K bottleneck
      a0 = a0 / (1.f + __expf(-a0));
      a1 = a1 / (1.f + __expf(-a1));
      a2 = a2 / (1.f + __expf(-a2));
      a3 = a3 / (1.f + __expf(-a3));
    }
    tb[p][r][bn + 0] = a0; tb[p][r][bn + 1] = a1;
    tb[p][r][bn + 2] = a2; tb[p][r][bn + 3] = a3;
  }
  __syncthreads();

  for (int task = tid; task < 1536; task += 256) {
    const int cq = task & 127;
    const int pr = task >> 7;
    const int rq = pr & 3;
    const int p  = pr >> 2;
    const int c  = cq * 4, r0 = rq * 4;
    const float* w2 = (p == 0) ? wq2 : (p == 1) ? wk2 : wv2;
    float acc[4][4];
    #pragma unroll
    for (int i = 0; i < 4; ++i)
      #pragma unroll
      for (int j = 0; j < 4; ++j) acc[i][j] = 0.f;

    for (int jb = 0; jb < 10; ++jb) {
      const float4 w0 = *(const float4*)(w2 + (jb * 4 + 0) * INNER + c);
      const float4 w1r = *(const float4*)(w2 + (jb * 4 + 1) * INNER + c);
      const float4 w2r = *(const float4*)(w2 + (jb * 4 + 2) * INNER + c);
      const float4 w3 = *(const float4*)(w2 + (jb * 4 + 3) * INNER + c);
      #pragma unroll
      for (int ri = 0; ri < 4; ++ri) {
        const float4 tv = *(const float4*)(&tb[p][r0 + ri][jb * 4]);
        acc[ri][0] += tv.x * w0.x + tv.y * w1r.x + tv.z * w2r.x + tv.w * w3.x;
        acc[ri][1] += tv.x * w0.y + tv.y * w1r.y + tv.z * w2r.y + tv.w * w3.y;
        acc[ri][2] += tv.x * w0.z + tv.y * w1r.z + tv.z * w2r.z + tv.w * w3.z;
        acc[ri][3] += tv.x * w0.w + tv.y * w1r.w + tv.z * w2r.w + tv.w * w3.w;
      }
    }
    #pragma unroll
    for (int ri = 0; ri < 4; ++ri) {
      const int n = n0 + r0 + ri;
      #pragma unroll
      for (int ci = 0; ci < 4; ++ci) {
        const int cc = c + ci;
        const int h = cc >> 6, d = cc & 63;
        const float v = acc[ri][ci];
        if (p == 0)
          Qg[((size_t)b * SEQ + h * NSEQ + n) * DH + d] = __float2bfloat16(v * QSCALE);
        else if (p == 1)
          Kg[((size_t)b * SEQ + h * NSEQ + n) * DH + d] = __float2bfloat16(v);
        else
          VTg[(((size_t)b * H_ + h) * DH + d) * NSEQ + n] = __float2bfloat16(v);
      }
    }
  }
}

// ---------------- kernel 2: attention, zero-barrier main loop ----------------
// grid (128 q-tiles of 64 rows, 4 batches) x 256 threads = 4 waves.
// Each wave: all 64 q-rows x its private 2048-kv range (strip pairs of 32).
// S^T = K*Q^T -> P stays in-lane for PV (k-relabeled across the strip pair).
struct PairBuf {
  bf16x8 k[2][2];   // [strip][k-span]   K rows (A-frags for S^T)
  bf16x4 v[2][4];   // [strip][d-tile]   V^T 8B pieces (PV B-frag halves)
};

__global__ __launch_bounds__(256, 2) void attn_kernel(
    const __hip_bfloat16* __restrict__ Qg,
    const __hip_bfloat16* __restrict__ Kg,
    const __hip_bfloat16* __restrict__ VTg,
    float* __restrict__ Og)
{
  __shared__ float Osh[4][64][68];   // per-wave partial O (pitch 68: 2-way only)
  __shared__ float psums[4][64];

  const int tid  = threadIdx.x;
  const int wave = tid >> 6;
  const int lane = tid & 63;
  const int lrow = lane & 15;
  const int quad = lane >> 4;
  const int b     = blockIdx.y;
  const int qbase = blockIdx.x * 64;

  const __hip_bfloat16* Qb = Qg + ((size_t)b * SEQ + qbase) * DH;
  const __hip_bfloat16* Kb = Kg + (size_t)b * SEQ * DH;
  const __hip_bfloat16* Vb = VTg + (size_t)b * (H_ * DH * NSEQ);

  // Q fragments (B-operand for S^T: contiguous 16B of Q rows), whole loop
  bf16x8 qf[4][2];
  #pragma unroll
  for (int mt = 0; mt < 4; ++mt)
    #pragma unroll
    for (int s = 0; s < 2; ++s)
      qf[mt][s] = *(const bf16x8*)(Qb + (mt * 16 + lrow) * DH + s * 32 + quad * 8);

  floatx4 oacc[4][4];   // [mt][dnt]: O[q=qbase+mt*16+quad*4+r][d=dnt*16+lrow]
  #pragma unroll
  for (int mt = 0; mt < 4; ++mt)
    #pragma unroll
    for (int dnt = 0; dnt < 4; ++dnt)
      oacc[mt][dnt] = (floatx4){0.f, 0.f, 0.f, 0.f};
  float psum[4] = {0.f, 0.f, 0.f, 0.f};   // per-lane partial row sums, q=mt*16+lrow

  const int kvbase = wave * 2048;   // this wave's private kv range

  auto load_pair = [&](PairBuf& pb, int pair) {
    const int kv0 = kvbase + pair * 32;
    const int h   = kv0 >> 10;          // strip pairs never cross a head
    const int n0  = kv0 & 1023;
    #pragma unroll
    for (int st = 0; st < 2; ++st) {
      #pragma unroll
      for (int ks = 0; ks < 2; ++ks)
        pb.k[st][ks] = *(const bf16x8*)(Kb + (size_t)(kv0 + st * 16 + lrow) * DH + ks * 32 + quad * 8);
      #pragma unroll
      for (int dnt = 0; dnt < 4; ++dnt)
        pb.v[st][dnt] = *(const bf16x4*)(Vb + (size_t)(h * DH + dnt * 16 + lrow) * NSEQ
                                         + n0 + st * 16 + quad * 4);
    }
  };

  auto compute_pair = [&](const PairBuf& pb) {
    // S^T per strip: C-layout -> lane holds P[q=lrow][kv=quad*4+r]
    bf16x8 pA[4];
    #pragma unroll
    for (int mt = 0; mt < 4; ++mt) {
      floatx4 s0 = (floatx4){0.f, 0.f, 0.f, 0.f};
      floatx4 s1 = (floatx4){0.f, 0.f, 0.f, 0.f};
      s0 = __builtin_amdgcn_mfma_f32_16x16x32_bf16(pb.k[0][0], qf[mt][0], s0, 0, 0, 0);
      s0 = __builtin_amdgcn_mfma_f32_16x16x32_bf16(pb.k[0][1], qf[mt][1], s0, 0, 0, 0);
      s1 = __builtin_amdgcn_mfma_f32_16x16x32_bf16(pb.k[1][0], qf[mt][0], s1, 0, 0, 0);
      s1 = __builtin_amdgcn_mfma_f32_16x16x32_bf16(pb.k[1][1], qf[mt][1], s1, 0, 0, 0);
      float p[8];
      #pragma unroll
      for (int r = 0; r < 4; ++r) {
        p[r]     = __builtin_amdgcn_exp2f(s0[r]);
        p[4 + r] = __builtin_amdgcn_exp2f(s1[r]);
      }
      psum[mt] += ((p[0] + p[1]) + (p[2] + p[3])) + ((p[4] + p[5]) + (p[6] + p[7]));
      bf16x8 pa;
      #pragma unroll
      for (int j = 0; j < 8; ++j) pa[j] = (__bf16)p[j];
      pA[mt] = pa;
    }
    // PV: K=32 spans both strips via consistent k-relabeling.
    // A: j<4 = strip0 r, j>=4 = strip1 r (in-lane). B: matching V^T pieces.
    #pragma unroll
    for (int dnt = 0; dnt < 4; ++dnt) {
      const bf16x8 vf = __builtin_shufflevector(pb.v[0][dnt], pb.v[1][dnt],
                                                0, 1, 2, 3, 4, 5, 6, 7);
      #pragma unroll
      for (int mt = 0; mt < 4; ++mt)
        oacc[mt][dnt] = __builtin_amdgcn_mfma_f32_16x16x32_bf16(pA[mt], vf, oacc[mt][dnt], 0, 0, 0);
    }
  };

  PairBuf buf0, buf1;
  load_pair(buf0, 0);
  #pragma unroll 2
  for (int pair = 0; pair < 64; ++pair) {
    PairBuf& cur = (pair & 1) ? buf1 : buf0;
    PairBuf& nxt = (pair & 1) ? buf0 : buf1;
    const int pn = (pair < 63) ? pair + 1 : 63;
    load_pair(nxt, pn);
    compute_pair(cur);
  }

  // per-lane psum covers this wave's kv for q=lrow; reduce over quads
  #pragma unroll
  for (int mt = 0; mt < 4; ++mt) {
    float s = psum[mt];
    s += __shfl_xor(s, 16, 64);
    s += __shfl_xor(s, 32, 64);
    psum[mt] = s;
  }
  if (quad == 0) {
    #pragma unroll
    for (int mt = 0; mt < 4; ++mt)
      psums[wave][mt * 16 + lrow] = psum[mt];
  }

  // stash partial O
  #pragma unroll
  for (int mt = 0; mt < 4; ++mt)
    #pragma unroll
    for (int dnt = 0; dnt < 4; ++dnt)
      #pragma unroll
      for (int r = 0; r < 4; ++r)
        Osh[wave][mt * 16 + quad * 4 + r][dnt * 16 + lrow] = oacc[mt][dnt][r];

  __syncthreads();   // the kernel's only barrier

  // merge 4 wave-partials, normalize, write O
  {
    const int q    = tid >> 2;
    const int dblk = (tid & 3) * 16;
    const float tot = psums[0][q] + psums[1][q] + psums[2][q] + psums[3][q];
    const float inv = 1.0f / tot;
    const size_t row = (size_t)b * SEQ + qbase + q;
    #pragma unroll
    for (int i = 0; i < 4; ++i) {
      const int d = dblk + i * 4;
      float4 a0 = *(const float4*)(&Osh[0][q][d]);
      float4 a1 = *(const float4*)(&Osh[1][q][d]);
      float4 a2 = *(const float4*)(&Osh[2][q][d]);
      float4 a3 = *(const float4*)(&Osh[3][q][d]);
      float4 res;
      res.x = (a0.x + a1.x + a2.x + a3.x) * inv;
      res.y = (a0.y + a1.y + a2.y + a3.y) * inv;
      res.z = (a0.z + a1.z + a2.z + a3.z) * inv;
      res.w = (a0.w + a1.w + a2.w + a3.w) * inv;
      *(float4*)(Og + row * DH + d) = res;
    }
  }
}

// ---------------- kernel 3: out = O @ wo + bo ----------------
__global__ __launch_bounds__(256) void out_kernel(
    const float* __restrict__ Og, const float* __restrict__ wo,
    const float* __restrict__ bo, float* __restrict__ out)
{
  const int tid = threadIdx.x;
  const int b  = blockIdx.x >> 6;
  const int n0 = (blockIdx.x & 63) << 4;

  __shared__ __align__(16) float os[16][512];
  for (int i = tid; i < 16 * 512; i += 256) {
    const int r = i >> 9, cc = i & 511;
    os[r][cc] = Og[((size_t)b * SEQ + (cc >> 6) * NSEQ + n0 + r) * DH + (cc & 63)];
  }
  __syncthreads();

  const int oq = tid & 63, rq = tid >> 6;
  const int o = oq * 4, r0 = rq * 4;
  float acc[4][4];
  #pragma unroll
  for (int i = 0; i < 4; ++i)
    #pragma unroll
    for (int j = 0; j < 4; ++j) acc[i][j] = 0.f;

  for (int jb = 0; jb < 128; ++jb) {
    const float4 w0 = *(const float4*)(wo + (jb * 4 + 0) * QS + o);
    const float4 w1 = *(const float4*)(wo + (jb * 4 + 1) * QS + o);
    const float4 w2 = *(const float4*)(wo + (jb * 4 + 2) * QS + o);
    const float4 w3 = *(const float4*)(wo + (jb * 4 + 3) * QS + o);
    #pragma unroll
    for (int ri = 0; ri < 4; ++ri) {
      const float4 ov = *(const float4*)(&os[r0 + ri][jb * 4]);
      acc[ri][0] += ov.x * w0.x + ov.y * w1.x + ov.z * w2.x + ov.w * w3.x;
      acc[ri][1] += ov.x * w0.y + ov.y * w1.y + ov.z * w2.y + ov.w * w3.y;
      acc[ri][2] += ov.x * w0.z + ov.y * w1.z + ov.z * w2.z + ov.w * w3.z;
      acc[ri][3] += ov.x * w0.w + ov.y * w1.w + ov.z * w2.w + ov.w * w3.w;
    }
  }

  const float4 bv = *(const float4*)(bo + o);
  #pragma unroll
  for (int ri = 0; ri < 4; ++ri) {
    float4 res;
    res.x = acc[ri][0] + bv.x;
    res.y = acc[ri][1] + bv.y;
    res.z = acc[ri][2] + bv.z;
    res.w = acc[ri][3] + bv.w;
    *(float4*)(out + ((size_t)b * NSEQ + n0 + r0 + ri) * QS + o) = res;
  }
}

extern "C" void kernel_launch(void* const* d_in, const int* in_sizes, int n_in,
                              void* d_out, int out_size, void* d_ws, size_t ws_size,
                              hipStream_t stream) {
  const float* x   = (const float*)d_in[0];
  const float* wq1 = (const float*)d_in[1];
  const float* wq2 = (const float*)d_in[2];
  const float* wk1 = (const float*)d_in[3];
  const float* wk2 = (const float*)d_in[4];
  const float* wv1 = (const float*)d_in[5];
  const float* wv2 = (const float*)d_in[6];
  const float* wo  = (const float*)d_in[7];
  const float* bo  = (const float*)d_in[8];
  float* out = (float*)d_out;

  __hip_bfloat16* Qg  = (__hip_bfloat16*)d_ws;
  __hip_bfloat16* Kg  = Qg + (size_t)B_ * SEQ * DH;
  __hip_bfloat16* VTg = Kg + (size_t)B_ * SEQ * DH;
  float*          Og  = (float*)(VTg + (size_t)B_ * SEQ * DH);

  qkv_kernel<<<256, 256, 0, stream>>>(x, wq1, wq2, wk1, wk2, wv1, wv2, Qg, Kg, VTg);
  attn_kernel<<<dim3(SEQ / 64, B_), 256, 0, stream>>>(Qg, Kg, VTg, Og);
  out_kernel<<<256, 256, 0, stream>>>(Og, wo, bo, out);
}

// Round 5
// 230.219 us; speedup vs baseline: 1.6469x; 1.4809x over previous
//
#include <hip/hip_runtime.h>
#include <hip/hip_bf16.h>

// CrossAttention: b=4, n=1024, qs=256, heads=8, dim_head=64, bottleneck=40.
// Attention = full 8192x8192 softmax-attention per batch over D=64.
//
// R5 = R4 + one-line fix (V_sw source read was missing the h*64 column
// offset -> all heads got head-0's V). K and V stored PRE-SWIZZLED in
// MFMA-fragment order so every attention-loop load is a fully-coalesced
// lane*16B global load. Zero-barrier main loop (S^T=K*Q^T keeps P in-lane
// for PV). XCD swizzle: one batch per XCD (2MB < 4MB L2).
//
// Workspace: Q 4MB | K_sw 4MB | V_sw 4MB (bf16) | O 8MB (fp32) = 20MB.

#define B_    4
#define H_    8
#define NSEQ  1024
#define SEQ   8192        // H_*NSEQ
#define DH    64
#define QS    256
#define INNER 512
#define QSCALE 0.18033688011112042f   // (1/sqrt(64)) * log2(e)

#define KVSW_BATCH 524288             // elems per batch in K_sw / V_sw

typedef __bf16 bf16x8 __attribute__((ext_vector_type(8)));
typedef float floatx4 __attribute__((ext_vector_type(4)));

// ---------------- kernel 1: QKV projections + fragment-order swizzle ----------------
// grid 256 (b * n/16), 256 threads. Outputs:
//   Qg  [b][h*1024+n][64]                       (row-major)
//   KSg [b][t16=kv>>4][ks=d>>5][lane][j]   lane=((d>>3)&3)*16 + (kv&15), j=d&7
//   VSg [b][p=kv>>5][dnt=d>>4][lane][j]    lane=((kv>>2)&3)*16 + (d&15), j=((kv>>4)&1)*4+(kv&3)
__global__ __launch_bounds__(256) void qkv_kernel(
    const float* __restrict__ x,
    const float* __restrict__ wq1, const float* __restrict__ wq2,
    const float* __restrict__ wk1, const float* __restrict__ wk2,
    const float* __restrict__ wv1, const float* __restrict__ wv2,
    __hip_bfloat16* __restrict__ Qg, __hip_bfloat16* __restrict__ KSg,
    __hip_bfloat16* __restrict__ VSg)
{
  const int tid  = threadIdx.x;
  const int blk  = blockIdx.x;
  const int b    = blk >> 6;
  const int nblk = blk & 63;
  const int n0   = nblk << 4;

  __shared__ __align__(16) float xs[16][256];
  __shared__ __align__(16) float tb[3][16][40];
  __shared__ __align__(16) __hip_bfloat16 qb[16][520];   // [n_local][h*64+d]
  __shared__ __align__(16) __hip_bfloat16 kb[16][520];
  __shared__ __align__(16) __hip_bfloat16 vb[512][20];   // transposed: [h*64+d][n_local]

  for (int i = tid; i < 16 * 256; i += 256) {
    const int r = i >> 8, c = i & 255;
    xs[r][c] = x[((size_t)b * NSEQ + n0 + r) * QS + c];
  }
  __syncthreads();

  // stage 1: bottleneck
  for (int qd = tid; qd < 480; qd += 256) {
    const int p   = qd / 160;
    const int rem = qd - p * 160;
    const int r   = rem / 10;
    const int bn  = (rem - r * 10) * 4;
    const float* w1 = (p == 0) ? wq1 : (p == 1) ? wk1 : wv1;
    float a0 = 0.f, a1 = 0.f, a2 = 0.f, a3 = 0.f;
    for (int c4 = 0; c4 < 64; ++c4) {
      const float4 xv = *(const float4*)(&xs[r][c4 * 4]);
      const float4 wa = *(const float4*)(w1 + (c4 * 4 + 0) * 40 + bn);
      const float4 wb = *(const float4*)(w1 + (c4 * 4 + 1) * 40 + bn);
      const float4 wc = *(const float4*)(w1 + (c4 * 4 + 2) * 40 + bn);
      const float4 wd = *(const float4*)(w1 + (c4 * 4 + 3) * 40 + bn);
      a0 += xv.x * wa.x + xv.y * wb.x + xv.z * wc.x + xv.w * wd.x;
      a1 += xv.x * wa.y + xv.y * wb.y + xv.z * wc.y + xv.w * wd.y;
      a2 += xv.x * wa.z + xv.y * wb.z + xv.z * wc.z + xv.w * wd.z;
      a3 += xv.x * wa.w + xv.y * wb.w + xv.z * wc.w + xv.w * wd.w;
    }
    if (p == 1) {   // SiLU on K bottleneck
      a0 = a0 / (1.f + __expf(-a0));
      a1 = a1 / (1.f + __expf(-a1));
      a2 = a2 / (1.f + __expf(-a2));
      a3 = a3 / (1.f + __expf(-a3));
    }
    tb[p][r][bn + 0] = a0; tb[p][r][bn + 1] = a1;
    tb[p][r][bn + 2] = a2; tb[p][r][bn + 3] = a3;
  }
  __syncthreads();

  // stage 2: project to 512, results into LDS (bf16)
  for (int task = tid; task < 1536; task += 256) {
    const int cq = task & 127;
    const int pr = task >> 7;
    const int rq = pr & 3;
    const int p  = pr >> 2;
    const int c  = cq * 4, r0 = rq * 4;
    const float* w2 = (p == 0) ? wq2 : (p == 1) ? wk2 : wv2;
    float acc[4][4];
    #pragma unroll
    for (int i = 0; i < 4; ++i)
      #pragma unroll
      for (int j = 0; j < 4; ++j) acc[i][j] = 0.f;

    for (int jb = 0; jb < 10; ++jb) {
      const float4 w0 = *(const float4*)(w2 + (jb * 4 + 0) * INNER + c);
      const float4 w1r = *(const float4*)(w2 + (jb * 4 + 1) * INNER + c);
      const float4 w2r = *(const float4*)(w2 + (jb * 4 + 2) * INNER + c);
      const float4 w3 = *(const float4*)(w2 + (jb * 4 + 3) * INNER + c);
      #pragma unroll
      for (int ri = 0; ri < 4; ++ri) {
        const float4 tv = *(const float4*)(&tb[p][r0 + ri][jb * 4]);
        acc[ri][0] += tv.x * w0.x + tv.y * w1r.x + tv.z * w2r.x + tv.w * w3.x;
        acc[ri][1] += tv.x * w0.y + tv.y * w1r.y + tv.z * w2r.y + tv.w * w3.y;
        acc[ri][2] += tv.x * w0.z + tv.y * w1r.z + tv.z * w2r.z + tv.w * w3.z;
        acc[ri][3] += tv.x * w0.w + tv.y * w1r.w + tv.z * w2r.w + tv.w * w3.w;
      }
    }
    #pragma unroll
    for (int ri = 0; ri < 4; ++ri)
      #pragma unroll
      for (int ci = 0; ci < 4; ++ci) {
        const int cc = c + ci;
        const float v = acc[ri][ci];
        if (p == 0)      qb[r0 + ri][cc] = __float2bfloat16(v * QSCALE);
        else if (p == 1) kb[r0 + ri][cc] = __float2bfloat16(v);
        else             vb[cc][r0 + ri] = __float2bfloat16(v);
      }
  }
  __syncthreads();

  // ---- Q write pass: row-major, coalesced ----
  {
    const int row = tid >> 4;
    const int col = (tid & 15) * 32;
    const int h = col >> 6, d0 = col & 63;
    __hip_bfloat16* dst = Qg + ((size_t)b * SEQ + h * NSEQ + n0 + row) * DH + d0;
    #pragma unroll
    for (int i = 0; i < 4; ++i)
      *(float4*)(dst + i * 8) = *(const float4*)(&qb[row][col + i * 8]);
  }

  // ---- K_sw write pass: fragment order, 16B coalesced chunks ----
  #pragma unroll
  for (int cc4 = 0; cc4 < 4; ++cc4) {
    const int c    = tid + cc4 * 256;          // [0,1024)
    const int h    = c >> 7;
    const int ks   = (c >> 6) & 1;
    const int lane = c & 63;
    const int lrow = lane & 15, quad = lane >> 4;
    const int t    = h * 64 + nblk;
    const size_t dst = (size_t)b * KVSW_BATCH + ((size_t)(t * 2 + ks) * 64 + lane) * 8;
    *(float4*)(KSg + dst) = *(const float4*)(&kb[lrow][h * 64 + ks * 32 + quad * 8]);
  }

  // ---- V_sw write pass: fragment order, 8B chunks ----
  {
    const int st = nblk & 1;                   // which 16-row half of the 32-kv pair
    #pragma unroll
    for (int cc8 = 0; cc8 < 8; ++cc8) {
      const int c    = tid + cc8 * 256;        // [0,2048)
      const int h    = c >> 8;
      const int dnt  = (c >> 6) & 3;
      const int lane = c & 63;
      const int lrow = lane & 15, quad = lane >> 4;
      const int p    = h * 32 + (nblk >> 1);
      const size_t dst = (size_t)b * KVSW_BATCH + ((size_t)(p * 4 + dnt) * 64 + lane) * 8 + st * 4;
      *(uint2*)(VSg + dst) = *(const uint2*)(&vb[h * 64 + dnt * 16 + lrow][quad * 4]);  // R5 fix: +h*64
    }
  }
}

// ---------------- kernel 2: attention, zero-barrier loop, coalesced frag loads ----------------
// grid 512 1-D (XCD-swizzled: batch = f(blk%8) so each XCD serves one batch),
// 256 threads = 4 waves; each wave: 64 q-rows x its private 2048-kv range.
struct PairBuf {
  bf16x8 k[2][2];   // [strip][k-span]
  bf16x8 v[4];      // [d-tile] (both strips packed, k-relabeled)
};

__global__ __launch_bounds__(256, 2) void attn_kernel(
    const __hip_bfloat16* __restrict__ Qg,
    const __hip_bfloat16* __restrict__ KSg,
    const __hip_bfloat16* __restrict__ VSg,
    float* __restrict__ Og)
{
  __shared__ float Osh[4][64][68];
  __shared__ float psums[4][64];

  const int tid  = threadIdx.x;
  const int wave = tid >> 6;
  const int lane = tid & 63;
  const int lrow = lane & 15;
  const int quad = lane >> 4;

  const int xcd   = blockIdx.x & 7;
  const int idx   = blockIdx.x >> 3;
  const int b     = xcd >> 1;
  const int qtile = (xcd & 1) * 64 + idx;
  const int qbase = qtile * 64;

  const __hip_bfloat16* Qb  = Qg + ((size_t)b * SEQ + qbase) * DH;
  const __hip_bfloat16* kp0 = KSg + (size_t)b * KVSW_BATCH + (size_t)wave * 131072 + lane * 8;
  const __hip_bfloat16* vp0 = VSg + (size_t)b * KVSW_BATCH + (size_t)wave * 131072 + lane * 8;

  // Q fragments in registers for the whole loop
  bf16x8 qf[4][2];
  #pragma unroll
  for (int mt = 0; mt < 4; ++mt)
    #pragma unroll
    for (int s = 0; s < 2; ++s)
      qf[mt][s] = *(const bf16x8*)(Qb + (mt * 16 + lrow) * DH + s * 32 + quad * 8);

  floatx4 oacc[4][4];   // [mt][dnt]: O[q=mt*16+quad*4+r][d=dnt*16+lrow]
  #pragma unroll
  for (int mt = 0; mt < 4; ++mt)
    #pragma unroll
    for (int dnt = 0; dnt < 4; ++dnt)
      oacc[mt][dnt] = (floatx4){0.f, 0.f, 0.f, 0.f};
  float psum[4] = {0.f, 0.f, 0.f, 0.f};   // per-lane partials, q = mt*16+lrow

  auto load_pair = [&](PairBuf& pb, int pair) {
    const __hip_bfloat16* kp = kp0 + pair * 2048;
    pb.k[0][0] = *(const bf16x8*)(kp);
    pb.k[0][1] = *(const bf16x8*)(kp + 512);
    pb.k[1][0] = *(const bf16x8*)(kp + 1024);
    pb.k[1][1] = *(const bf16x8*)(kp + 1536);
    const __hip_bfloat16* vp = vp0 + pair * 2048;
    #pragma unroll
    for (int dnt = 0; dnt < 4; ++dnt)
      pb.v[dnt] = *(const bf16x8*)(vp + dnt * 512);
  };

  auto compute_pair = [&](const PairBuf& pb) {
    bf16x8 pA[4];
    #pragma unroll
    for (int mt = 0; mt < 4; ++mt) {
      floatx4 s0 = (floatx4){0.f, 0.f, 0.f, 0.f};
      floatx4 s1 = (floatx4){0.f, 0.f, 0.f, 0.f};
      s0 = __builtin_amdgcn_mfma_f32_16x16x32_bf16(pb.k[0][0], qf[mt][0], s0, 0, 0, 0);
      s0 = __builtin_amdgcn_mfma_f32_16x16x32_bf16(pb.k[0][1], qf[mt][1], s0, 0, 0, 0);
      s1 = __builtin_amdgcn_mfma_f32_16x16x32_bf16(pb.k[1][0], qf[mt][0], s1, 0, 0, 0);
      s1 = __builtin_amdgcn_mfma_f32_16x16x32_bf16(pb.k[1][1], qf[mt][1], s1, 0, 0, 0);
      float p[8];
      #pragma unroll
      for (int r = 0; r < 4; ++r) {
        p[r]     = __builtin_amdgcn_exp2f(s0[r]);
        p[4 + r] = __builtin_amdgcn_exp2f(s1[r]);
      }
      psum[mt] += ((p[0] + p[1]) + (p[2] + p[3])) + ((p[4] + p[5]) + (p[6] + p[7]));
      bf16x8 pa;
      #pragma unroll
      for (int j = 0; j < 8; ++j) pa[j] = (__bf16)p[j];
      pA[mt] = pa;
    }
    #pragma unroll
    for (int dnt = 0; dnt < 4; ++dnt)
      #pragma unroll
      for (int mt = 0; mt < 4; ++mt)
        oacc[mt][dnt] = __builtin_amdgcn_mfma_f32_16x16x32_bf16(pA[mt], pb.v[dnt], oacc[mt][dnt], 0, 0, 0);
  };

  PairBuf buf0, buf1;
  load_pair(buf0, 0);
  #pragma unroll 2
  for (int pair = 0; pair < 64; ++pair) {
    PairBuf& cur = (pair & 1) ? buf1 : buf0;
    PairBuf& nxt = (pair & 1) ? buf0 : buf1;
    const int pn = (pair < 63) ? pair + 1 : 63;
    load_pair(nxt, pn);
    compute_pair(cur);
  }

  // psum: reduce over quads (lane's q = mt*16+lrow)
  #pragma unroll
  for (int mt = 0; mt < 4; ++mt) {
    float s = psum[mt];
    s += __shfl_xor(s, 16, 64);
    s += __shfl_xor(s, 32, 64);
    psum[mt] = s;
  }
  if (quad == 0) {
    #pragma unroll
    for (int mt = 0; mt < 4; ++mt)
      psums[wave][mt * 16 + lrow] = psum[mt];
  }

  #pragma unroll
  for (int mt = 0; mt < 4; ++mt)
    #pragma unroll
    for (int dnt = 0; dnt < 4; ++dnt)
      #pragma unroll
      for (int r = 0; r < 4; ++r)
        Osh[wave][mt * 16 + quad * 4 + r][dnt * 16 + lrow] = oacc[mt][dnt][r];

  __syncthreads();   // the kernel's only barrier

  {
    const int q    = tid >> 2;
    const int dblk = (tid & 3) * 16;
    const float tot = psums[0][q] + psums[1][q] + psums[2][q] + psums[3][q];
    const float inv = 1.0f / tot;
    const size_t row = (size_t)b * SEQ + qbase + q;
    #pragma unroll
    for (int i = 0; i < 4; ++i) {
      const int d = dblk + i * 4;
      float4 a0 = *(const float4*)(&Osh[0][q][d]);
      float4 a1 = *(const float4*)(&Osh[1][q][d]);
      float4 a2 = *(const float4*)(&Osh[2][q][d]);
      float4 a3 = *(const float4*)(&Osh[3][q][d]);
      float4 res;
      res.x = (a0.x + a1.x + a2.x + a3.x) * inv;
      res.y = (a0.y + a1.y + a2.y + a3.y) * inv;
      res.z = (a0.z + a1.z + a2.z + a3.z) * inv;
      res.w = (a0.w + a1.w + a2.w + a3.w) * inv;
      *(float4*)(Og + row * DH + d) = res;
    }
  }
}

// ---------------- kernel 3: out = O @ wo + bo ----------------
__global__ __launch_bounds__(256) void out_kernel(
    const float* __restrict__ Og, const float* __restrict__ wo,
    const float* __restrict__ bo, float* __restrict__ out)
{
  const int tid = threadIdx.x;
  const int b  = blockIdx.x >> 6;
  const int n0 = (blockIdx.x & 63) << 4;

  __shared__ __align__(16) float os[16][512];
  for (int i = tid; i < 16 * 512; i += 256) {
    const int r = i >> 9, cc = i & 511;
    os[r][cc] = Og[((size_t)b * SEQ + (cc >> 6) * NSEQ + n0 + r) * DH + (cc & 63)];
  }
  __syncthreads();

  const int oq = tid & 63, rq = tid >> 6;
  const int o = oq * 4, r0 = rq * 4;
  float acc[4][4];
  #pragma unroll
  for (int i = 0; i < 4; ++i)
    #pragma unroll
    for (int j = 0; j < 4; ++j) acc[i][j] = 0.f;

  for (int jb = 0; jb < 128; ++jb) {
    const float4 w0 = *(const float4*)(wo + (jb * 4 + 0) * QS + o);
    const float4 w1 = *(const float4*)(wo + (jb * 4 + 1) * QS + o);
    const float4 w2 = *(const float4*)(wo + (jb * 4 + 2) * QS + o);
    const float4 w3 = *(const float4*)(wo + (jb * 4 + 3) * QS + o);
    #pragma unroll
    for (int ri = 0; ri < 4; ++ri) {
      const float4 ov = *(const float4*)(&os[r0 + ri][jb * 4]);
      acc[ri][0] += ov.x * w0.x + ov.y * w1.x + ov.z * w2.x + ov.w * w3.x;
      acc[ri][1] += ov.x * w0.y + ov.y * w1.y + ov.z * w2.y + ov.w * w3.y;
      acc[ri][2] += ov.x * w0.z + ov.y * w1.z + ov.z * w2.z + ov.w * w3.z;
      acc[ri][3] += ov.x * w0.w + ov.y * w1.w + ov.z * w2.w + ov.w * w3.w;
    }
  }

  const float4 bv = *(const float4*)(bo + o);
  #pragma unroll
  for (int ri = 0; ri < 4; ++ri) {
    float4 res;
    res.x = acc[ri][0] + bv.x;
    res.y = acc[ri][1] + bv.y;
    res.z = acc[ri][2] + bv.z;
    res.w = acc[ri][3] + bv.w;
    *(float4*)(out + ((size_t)b * NSEQ + n0 + r0 + ri) * QS + o) = res;
  }
}

extern "C" void kernel_launch(void* const* d_in, const int* in_sizes, int n_in,
                              void* d_out, int out_size, void* d_ws, size_t ws_size,
                              hipStream_t stream) {
  const float* x   = (const float*)d_in[0];
  const float* wq1 = (const float*)d_in[1];
  const float* wq2 = (const float*)d_in[2];
  const float* wk1 = (const float*)d_in[3];
  const float* wk2 = (const float*)d_in[4];
  const float* wv1 = (const float*)d_in[5];
  const float* wv2 = (const float*)d_in[6];
  const float* wo  = (const float*)d_in[7];
  const float* bo  = (const float*)d_in[8];
  float* out = (float*)d_out;

  __hip_bfloat16* Qg  = (__hip_bfloat16*)d_ws;
  __hip_bfloat16* KSg = Qg + (size_t)B_ * SEQ * DH;
  __hip_bfloat16* VSg = KSg + (size_t)B_ * KVSW_BATCH;
  float*          Og  = (float*)(VSg + (size_t)B_ * KVSW_BATCH);

  qkv_kernel<<<256, 256, 0, stream>>>(x, wq1, wq2, wk1, wk2, wv1, wv2, Qg, KSg, VSg);
  attn_kernel<<<512, 256, 0, stream>>>(Qg, KSg, VSg, Og);
  out_kernel<<<256, 256, 0, stream>>>(Og, wo, bo, out);
}